// Round 5
// baseline (181.451 us; speedup 1.0000x reference)
//
#include <hip/hip_runtime.h>
#include <hip/hip_bf16.h>

typedef __attribute__((ext_vector_type(8))) __bf16 bf16x8;
typedef __attribute__((ext_vector_type(8))) ushort ushort8;
typedef __attribute__((ext_vector_type(4))) float floatx4;

union FragU { ushort8 u; bf16x8 b; unsigned d[4]; };

__device__ inline ushort bf1(float a){
  unsigned u = __float_as_uint(a);
  return (ushort)((u + 0x7FFFu + ((u >> 16) & 1u)) >> 16);   // RNE fp32->bf16
}
// packed RNE fp32x2 -> bf16x2 (v_cvt_pk_bf16_f32 on gfx950)
__device__ inline unsigned cvt_pk(float a, float b){
  union { __hip_bfloat162 h; unsigned u; } c;
  c.h = __float22bfloat162_rn(float2{a, b});
  return c.u;   // low16 = bf16(a), high16 = bf16(b)
}

#define BLOCKS 1024

// Per-wave pipeline, NO barriers (h2 LDS slice is wave-private; DS ops of a
// wave are processed in order, so write->read RAW is safe without s_barrier —
// this avoids the s_waitcnt vmcnt(0) drain the compiler emits before barriers,
// letting stores/prefetch stay in flight across iterations):
//   conv1 fp32 VALU -> A-frags F0/F1/F2 (k-order kw*32+ic)
//   conv2 = 2 GEMMs K=64 via 8 MFMA (W2 B-frags in VGPR)
//   h2 transpose via per-wave LDS slice (C-layout -> A-layout),
//     packed cols c = w*32 + 2*(oc2&15) + (oc2>>4)
//   linear K=64 via 8 MFMA (Wp B-frags in VGPR, N-permuted so lane lm
//     owns out cols 4*lm..4*lm+3) -> nontemporal float4 coalesced stores
__global__ __launch_bounds__(256) void cnn_fused(
    const float* __restrict__ x,  const float* __restrict__ W1,
    const float* __restrict__ b1, const float* __restrict__ W2,
    const float* __restrict__ b2, const float* __restrict__ Wp,
    const float* __restrict__ bp, float* __restrict__ out, int niter)
{
  __shared__ __align__(16) ushort h2buf[4 * 16 * 72];  // 9216 B, per-wave slices
  const int tid  = threadIdx.x;
  const int wid  = tid >> 6;
  const int lane = tid & 63;
  const int lm   = lane & 15;
  const int quad = lane >> 4;
  ushort*   myh2 = &h2buf[wid * (16 * 72)];
  unsigned* h2d  = (unsigned*)myh2;                    // dword view, row stride 36

  // ---- loop-invariant register fragments ----
  // conv2 B-frags: lane supplies B[k = h*32 + quad*8+j][n = tt*16+lm],
  // k-order kw*32+ic  ->  W2 flat [oc2][ic][kw] index = oc2*64 + ic*2 + kw
  FragU w2f[2][2];   // [oc2-tile][k-half]
  #pragma unroll
  for (int t = 0; t < 2; ++t)
    #pragma unroll
    for (int h = 0; h < 2; ++h)
      #pragma unroll
      for (int j = 0; j < 8; ++j)
        w2f[t][h].u[j] = bf1(W2[(t*16 + lm)*64 + (quad*8 + j)*2 + h]);

  // linear B-frags: out col o = 4*lm + t; storage col c = h*32 + quad*8 + j;
  // c -> (w = c>>5, oc2 = ((c&31)>>1) | ((c&1)<<4)); Wp flat = o*64 + oc2*2 + w
  FragU wpf[4][2];   // [t = o%4][k-half]
  #pragma unroll
  for (int t = 0; t < 4; ++t)
    #pragma unroll
    for (int h = 0; h < 2; ++h)
      #pragma unroll
      for (int j = 0; j < 8; ++j){
        const int c   = h*32 + quad*8 + j;
        const int cp  = c & 31;
        const int oc2 = (cp >> 1) | ((cp & 1) << 4);
        wpf[t][h].u[j] = bf1(Wp[(4*lm + t)*64 + oc2*2 + h]);
      }

  // conv1 weights for ic = quad*8..quad*8+7 (this lane's A-frag k-range)
  float w1r[8][4], b1r[8];
  #pragma unroll
  for (int i = 0; i < 8; ++i){
    const int oc = quad*8 + i;
    w1r[i][0] = W1[oc*4+0]; w1r[i][1] = W1[oc*4+1];
    w1r[i][2] = W1[oc*4+2]; w1r[i][3] = W1[oc*4+3];
    b1r[i]    = b1[oc];
  }
  const float  b2a = b2[lm], b2b = b2[16 + lm];
  const float4 bp4 = ((const float4*)bp)[lm];          // bp[4*lm .. 4*lm+3]

  // ---- per-wave contiguous row range ----
  const long gw = (long)blockIdx.x * 4 + wid;
  long tilebase = gw * ((long)niter * 16);

  const float4* x4 = (const float4*)x;
  float4 xa = x4[2*(tilebase + lm)];
  float4 xb = x4[2*(tilebase + lm) + 1];

  const floatx4 z = {0.f, 0.f, 0.f, 0.f};

  for (int it = 0; it < niter; ++it){
    // prefetch next tile's x (stays in flight; no barrier drains it)
    float4 nxa, nxb;
    if (it + 1 < niter){
      const long nr = tilebase + 16 + lm;
      nxa = x4[2*nr]; nxb = x4[2*nr + 1];
    }

    // ---- conv1 (fp32): row lm, ic = quad*8+i, 3 windows; packed cvt ----
    FragU F0, F1, F2;
    #pragma unroll
    for (int i = 0; i < 8; i += 2){
      const float p00 = w1r[i][0],   p01 = w1r[i][1];
      const float p10 = w1r[i][2],   p11 = w1r[i][3],   pb = b1r[i];
      const float q00 = w1r[i+1][0], q01 = w1r[i+1][1];
      const float q10 = w1r[i+1][2], q11 = w1r[i+1][3], qb = b1r[i+1];
      const float a0 = fmaxf(0.f, pb + p00*xa.x + p01*xa.y + p10*xb.x + p11*xb.y);
      const float a1 = fmaxf(0.f, pb + p00*xa.y + p01*xa.z + p10*xb.y + p11*xb.z);
      const float a2 = fmaxf(0.f, pb + p00*xa.z + p01*xa.w + p10*xb.z + p11*xb.w);
      const float c0 = fmaxf(0.f, qb + q00*xa.x + q01*xa.y + q10*xb.x + q11*xb.y);
      const float c1 = fmaxf(0.f, qb + q00*xa.y + q01*xa.z + q10*xb.y + q11*xb.z);
      const float c2 = fmaxf(0.f, qb + q00*xa.z + q01*xa.w + q10*xb.z + q11*xb.w);
      F0.d[i>>1] = cvt_pk(a0, c0);
      F1.d[i>>1] = cvt_pk(a1, c1);
      F2.d[i>>1] = cvt_pk(a2, c2);
    }

    // ---- conv2: acc[g][tt], g = out window (w), tt = oc2-tile ----
    floatx4 a00 = z, a01 = z, a10 = z, a11 = z;
    a00 = __builtin_amdgcn_mfma_f32_16x16x32_bf16(F0.b, w2f[0][0].b, a00, 0,0,0);
    a00 = __builtin_amdgcn_mfma_f32_16x16x32_bf16(F1.b, w2f[0][1].b, a00, 0,0,0);
    a01 = __builtin_amdgcn_mfma_f32_16x16x32_bf16(F0.b, w2f[1][0].b, a01, 0,0,0);
    a01 = __builtin_amdgcn_mfma_f32_16x16x32_bf16(F1.b, w2f[1][1].b, a01, 0,0,0);
    a10 = __builtin_amdgcn_mfma_f32_16x16x32_bf16(F1.b, w2f[0][0].b, a10, 0,0,0);
    a10 = __builtin_amdgcn_mfma_f32_16x16x32_bf16(F2.b, w2f[0][1].b, a10, 0,0,0);
    a11 = __builtin_amdgcn_mfma_f32_16x16x32_bf16(F1.b, w2f[1][0].b, a11, 0,0,0);
    a11 = __builtin_amdgcn_mfma_f32_16x16x32_bf16(F2.b, w2f[1][1].b, a11, 0,0,0);

    // ---- epilogue conv2 -> h2 LDS (packed dwords, wave-private slice) ----
    #pragma unroll
    for (int rg = 0; rg < 4; ++rg){
      const int rr = (quad*4 + rg) * 36;
      h2d[rr +      lm] = cvt_pk(fmaxf(0.f, a00[rg] + b2a), fmaxf(0.f, a01[rg] + b2b));
      h2d[rr + 16 + lm] = cvt_pk(fmaxf(0.f, a10[rg] + b2a), fmaxf(0.f, a11[rg] + b2b));
    }

    // ---- stage C A-frags (same-wave DS RAW: in-order, lgkmcnt-protected) ----
    FragU ca0, ca1;
    ca0.u = *(const ushort8*)&myh2[lm*72 +      quad*8];
    ca1.u = *(const ushort8*)&myh2[lm*72 + 32 + quad*8];

    // ---- linear: 4 N-tiles (t = o%4) ----
    floatx4 oacc[4];
    #pragma unroll
    for (int t = 0; t < 4; ++t){
      floatx4 acc = z;
      acc = __builtin_amdgcn_mfma_f32_16x16x32_bf16(ca0.b, wpf[t][0].b, acc, 0,0,0);
      acc = __builtin_amdgcn_mfma_f32_16x16x32_bf16(ca1.b, wpf[t][1].b, acc, 0,0,0);
      oacc[t] = acc;
    }

    // ---- coalesced nontemporal floatx4 stores: lane lm owns cols 4*lm.. ----
    #pragma unroll
    for (int rg = 0; rg < 4; ++rg){
      floatx4 v;
      v[0] = oacc[0][rg] + bp4.x;
      v[1] = oacc[1][rg] + bp4.y;
      v[2] = oacc[2][rg] + bp4.z;
      v[3] = oacc[3][rg] + bp4.w;
      __builtin_nontemporal_store(v, (floatx4*)(out + (tilebase + quad*4 + rg)*64 + 4*lm));
    }

    if (it + 1 < niter){ xa = nxa; xb = nxb; tilebase += 16; }
  }
}

extern "C" void kernel_launch(void* const* d_in, const int* in_sizes, int n_in,
                              void* d_out, int out_size, void* d_ws, size_t ws_size,
                              hipStream_t stream)
{
  const float* x  = (const float*)d_in[0];
  const float* W1 = (const float*)d_in[1];
  const float* b1 = (const float*)d_in[2];
  const float* W2 = (const float*)d_in[3];
  const float* b2 = (const float*)d_in[4];
  const float* Wp = (const float*)d_in[5];
  const float* bp = (const float*)d_in[6];
  float* out = (float*)d_out;

  const int rows  = in_sizes[0] / 8;            // B*S = 524288
  const int tiles = rows / 16;                  // 32768 wave-tiles
  const int niter = tiles / (BLOCKS * 4);       // 8
  cnn_fused<<<BLOCKS, 256, 0, stream>>>(x, W1, b1, W2, b2, Wp, bp, out, niter);
}